// Round 5
// baseline (236.460 us; speedup 1.0000x reference)
//
#include <hip/hip_runtime.h>
#include <hip/hip_fp16.h>
#include <hip/hip_cooperative_groups.h>

namespace cg = cooperative_groups;

#define T_DIM 2048
#define S_DIM 2048
#define B_DIM 2
#define E_DIM 256
#define H_DIM 8
#define DH 32

typedef _Float16 half8 __attribute__((ext_vector_type(8)));
typedef _Float16 half4 __attribute__((ext_vector_type(4)));
typedef float floatx4 __attribute__((ext_vector_type(4)));

// v_exp_f32 computes 2^x. Fold log2(e) into the Q scale so exp(s) == exp2(s').
#if defined(__has_builtin)
#if __has_builtin(__builtin_amdgcn_exp2f)
#define EXPFN(x) __builtin_amdgcn_exp2f(x)
#define LOG2E_FOLD 1.4426950408889634f
#endif
#endif
#ifndef EXPFN
#define EXPFN(x) __expf(x)
#define LOG2E_FOLD 1.0f
#endif

#define XS 264      // 256 + 8 halves pad
#define OSTRIDE 36
#define ASTRIDE 132

#define ATTN_STEP(cur, nxt, PRE)                                                \
  {                                                                             \
    if (PRE) {                                                                  \
      kf[nxt] = *(const half8*)kp;                                              \
      v0[nxt] = *(const half4*)vp;                                              \
      v1[nxt] = *(const half4*)(vp + 256);                                      \
      kp += 512; vp += 512;                                                     \
    }                                                                           \
    _Pragma("unroll")                                                           \
    for (int j = 0; j < 4; ++j) {                                               \
      floatx4 c = {0.f, 0.f, 0.f, 0.f};                                         \
      c = __builtin_amdgcn_mfma_f32_16x16x32_f16(kf[cur], qf[j], c, 0, 0, 0);   \
      float e0 = EXPFN(c[0]), e1 = EXPFN(c[1]), e2 = EXPFN(c[2]), e3 = EXPFN(c[3]); \
      ls[j] += (e0 + e1) + (e2 + e3);                                           \
      half4 p;                                                                  \
      p[0] = (_Float16)e0; p[1] = (_Float16)e1;                                 \
      p[2] = (_Float16)e2; p[3] = (_Float16)e3;                                 \
      o[j][0] = __builtin_amdgcn_mfma_f32_16x16x16f16(p, v0[cur], o[j][0], 0, 0, 0); \
      o[j][1] = __builtin_amdgcn_mfma_f32_16x16x16f16(p, v1[cur], o[j][1], 0, 0, 0); \
    }                                                                           \
  }

// ===========================================================================
// Fused cooperative kernel: 256 blocks x 512 threads, guaranteed co-resident
// (1 block/CU: LDS 74 KB, VGPR cap 256). Phases separated by grid.sync().
//  A: Q/K projection + V transpose (two 256-thread half-blocks x 2 units)
//  B: attention+O (2 t-chunks per block; h == bx%8 == XCD for K/V L2 residency)
//  C: avg recompute (2 units per block) + outproj (one 64x64 tile per block;
//     64 r-blocks x 4 c-blocks = 256 units -> FULL 4096-row coverage.
//     Round-4 bug: 32-row tiles covered only rows 0..2047.)
// ===========================================================================
__global__ __launch_bounds__(512, 2) void fused_all(
    const float* __restrict__ Q, const float* __restrict__ K,
    const float* __restrict__ V,
    const float* __restrict__ Wq, const float* __restrict__ Wk,
    const float* __restrict__ bq, const float* __restrict__ bk,
    const float* __restrict__ Wo, const float* __restrict__ bo,
    _Float16* __restrict__ Qp, _Float16* __restrict__ Kp,
    _Float16* __restrict__ Vt2, _Float16* __restrict__ Of16,
    float* __restrict__ lsum, float* __restrict__ out,
    float* __restrict__ avg_out, float scale_q) {
  __shared__ __align__(16) char smem_raw[75776];  // 74 KB union
  cg::grid_group grid = cg::this_grid();
  int tid = threadIdx.x;
  int bx = blockIdx.x;

  // ---------------- Phase A: proj Q/K + V transpose ----------------
  {
    int tid2 = tid & 255;
    int half = tid >> 8;
    _Float16* hs = (_Float16*)(smem_raw + half * 33792);
    for (int uu = 0; uu < 2; ++uu) {
      int u = bx * 4 + half * 2 + uu;  // 0..1023
      // ---- part 1: global -> LDS (uniform barrier follows) ----
      if (u < 512) {
        int z = u >> 8;
        int rem = u & 255;
        int r0 = (rem >> 2) * 64;
        const float* X = z ? K : Q;
#pragma unroll
        for (int it = 0; it < 16; ++it) {
          int row = (tid2 >> 6) + it * 4, col = (tid2 & 63) * 4;
          float4 a = *(const float4*)(X + (size_t)(r0 + row) * 256 + col);
          half4 hx;
          hx[0] = (_Float16)a.x; hx[1] = (_Float16)a.y;
          hx[2] = (_Float16)a.z; hx[3] = (_Float16)a.w;
          *(half4*)(hs + row * XS + col) = hx;
        }
      } else {
        float (*tile)[33] = (float (*)[33])hs;  // 8.4 KB of the half's region
        int b2 = u - 512;
        int st = b2 & 31, h = (b2 >> 5) & 7, b = b2 >> 8;
        int s0 = st * 64;
        int d = tid2 & 31, sr = tid2 >> 5;
#pragma unroll
        for (int k = 0; k < 8; ++k) {
          int s = sr + k * 8;
          tile[s][d] = V[((size_t)(s0 + s) * B_DIM + b) * E_DIM + h * DH + d];
        }
      }
      __syncthreads();
      // ---- part 2: compute + store ----
      if (u < 512) {
        int z = u >> 8;
        int rem = u & 255;
        int r0 = (rem >> 2) * 64;
        int c0 = (rem & 3) * 64;
        const float* W = z ? Wk : Wq;
        const float* bias = z ? bk : bq;
        _Float16* outp = z ? Kp : Qp;
        float scale = z ? 1.0f : scale_q;
        int lane = tid2 & 63, w4 = tid2 >> 6;
        int quad = lane >> 4, l16 = lane & 15;
        floatx4 c[4] = {{0.f,0.f,0.f,0.f},{0.f,0.f,0.f,0.f},{0.f,0.f,0.f,0.f},{0.f,0.f,0.f,0.f}};
        int arow = w4 * 16 + l16;
        const float* Wr0 = W + (size_t)(c0 + l16) * 256 + quad * 8;
#pragma unroll 2
        for (int k0 = 0; k0 < 256; k0 += 32) {
          half8 af = *(const half8*)(hs + arow * XS + k0 + quad * 8);
#pragma unroll
          for (int j = 0; j < 4; ++j) {
            const float* Wr = Wr0 + j * 16 * 256 + k0;
            float4 w0 = *(const float4*)(Wr);
            float4 w1 = *(const float4*)(Wr + 4);
            half8 bf;
            bf[0] = (_Float16)w0.x; bf[1] = (_Float16)w0.y;
            bf[2] = (_Float16)w0.z; bf[3] = (_Float16)w0.w;
            bf[4] = (_Float16)w1.x; bf[5] = (_Float16)w1.y;
            bf[6] = (_Float16)w1.z; bf[7] = (_Float16)w1.w;
            c[j] = __builtin_amdgcn_mfma_f32_16x16x32_f16(af, bf, c[j], 0, 0, 0);
          }
        }
#pragma unroll
        for (int j = 0; j < 4; ++j) {
          int f = c0 + j * 16 + l16;
          float bv = bias[f];
          int h = f >> 5, d = f & 31;
#pragma unroll
          for (int r = 0; r < 4; ++r) {
            int row = r0 + w4 * 16 + quad * 4 + r;
            int t = row >> 1, b = row & 1;
            outp[(((size_t)b * H_DIM + h) * T_DIM + t) * DH + d] =
                (_Float16)((c[j][r] + bv) * scale);
          }
        }
      } else {
        float (*tile)[33] = (float (*)[33])hs;
        int b2 = u - 512;
        int st = b2 & 31, h = (b2 >> 5) & 7, b = b2 >> 8;
        int si = tid2 & 63, dq = tid2 >> 6;
        size_t base = ((size_t)b * H_DIM + h) * 128 * 512;
        int tl = st * 4 + (si >> 4);
        int sl = si & 15;
#pragma unroll
        for (int m = 0; m < 8; ++m) {
          int dd = dq * 8 + m;
          Vt2[base + (size_t)tl * 512 + dd * 16 + sl] = (_Float16)tile[si][dd];
        }
      }
      __syncthreads();
    }
  }
  grid.sync();

  // ---------------- Phase B: attention + O ----------------
  {
    float* stageO = (float*)smem_raw;            // [8][64*OSTRIDE]
    float* lstage = (float*)(smem_raw + 73728);  // [8][64]
    int lane = tid & 63, w = tid >> 6;
    int quad = lane >> 4, l16 = lane & 15;
    int h = bx & 7, b = (bx >> 3) & 1;
    const _Float16* KbBase = Kp + ((size_t)b * H_DIM + h) * S_DIM * DH;
    const _Float16* VbBase = Vt2 + ((size_t)b * H_DIM + h) * 128 * 512;
    for (int rep = 0; rep < 2; ++rep) {
      int t0 = (((bx >> 4) << 1) + rep) << 6;
      const _Float16* Qb = Qp + (((size_t)b * H_DIM + h) * T_DIM + t0) * DH;

      half8 qf[4];
#pragma unroll
      for (int j = 0; j < 4; ++j)
        qf[j] = *(const half8*)(Qb + (size_t)(j * 16 + l16) * DH + quad * 8);

      floatx4 o[4][2];
#pragma unroll
      for (int j = 0; j < 4; ++j) { o[j][0] = (floatx4){0,0,0,0}; o[j][1] = (floatx4){0,0,0,0}; }
      float ls[4] = {0.f, 0.f, 0.f, 0.f};

      int tile0 = w * 16;
      const _Float16* kp = KbBase + (size_t)(tile0 * 16 + l16) * DH + quad * 8;
      const _Float16* vp = VbBase + (size_t)tile0 * 512 + l16 * 16 + quad * 4;

      half8 kf[2];
      half4 v0[2], v1[2];
      kf[0] = *(const half8*)kp;
      v0[0] = *(const half4*)vp;
      v1[0] = *(const half4*)(vp + 256);
      kp += 512; vp += 512;

      for (int ii = 0; ii < 7; ++ii) {
        ATTN_STEP(0, 1, true);
        ATTN_STEP(1, 0, true);
      }
      ATTN_STEP(0, 1, true);
      ATTN_STEP(1, 0, false);

#pragma unroll
      for (int j = 0; j < 4; ++j) {
        float v = ls[j];
        v += __shfl_xor(v, 16, 64);
        v += __shfl_xor(v, 32, 64);
        if (quad == 0) lstage[w * 64 + j * 16 + l16] = v;
      }
#pragma unroll
      for (int j = 0; j < 4; ++j)
#pragma unroll
        for (int r = 0; r < 4; ++r) {
          stageO[w * 2304 + (j * 16 + quad * 4 + r) * OSTRIDE + l16] = o[j][0][r];
          stageO[w * 2304 + (j * 16 + quad * 4 + r) * OSTRIDE + 16 + l16] = o[j][1][r];
        }
      __syncthreads();

      int t = tid >> 3, d0 = (tid & 7) * 4;
      floatx4 os = {0.f, 0.f, 0.f, 0.f};
      float lr = 0.f;
#pragma unroll
      for (int ww = 0; ww < 8; ++ww) {
        os += *(const floatx4*)&stageO[ww * 2304 + t * OSTRIDE + d0];
        lr += lstage[ww * 64 + t];
      }
      float rl = 1.0f / lr;
      half4 oh;
      oh[0] = (_Float16)(os[0] * rl); oh[1] = (_Float16)(os[1] * rl);
      oh[2] = (_Float16)(os[2] * rl); oh[3] = (_Float16)(os[3] * rl);
      *(half4*)(Of16 + ((size_t)(t0 + t) * B_DIM + b) * E_DIM + h * DH + d0) = oh;
      if (tid < 64) {
        float s = 0.f;
#pragma unroll
        for (int ww = 0; ww < 8; ++ww) s += lstage[ww * 64 + tid];
        lsum[((size_t)b * H_DIM + h) * T_DIM + t0 + tid] = s;
      }
      __syncthreads();  // protect stageO/lstage for next rep
    }
  }
  grid.sync();

  // ---------------- Phase C: avg (x2) + outproj (64x64 tile, x1) ----------------
  {
    float* smemf = (float*)smem_raw;
    int lane = tid & 63, w = tid >> 6;
    int quad = lane >> 4, l16 = lane & 15;
    for (int rep = 0; rep < 2; ++rep) {
      int u = bx * 2 + rep;  // 0..511
      int sc = u & 15, tc = (u >> 4) & 15, b = u >> 8;
      int t0 = tc * 128, s0 = sc * 128;
      int tw = t0 + w * 16;

      floatx4 acc[8];
#pragma unroll
      for (int st = 0; st < 8; ++st) acc[st] = (floatx4){0.f, 0.f, 0.f, 0.f};

      const _Float16* qp = Qp + (size_t)b * H_DIM * T_DIM * DH +
                           (size_t)(tw + l16) * DH + quad * 8;
      const _Float16* kp = Kp + (size_t)b * H_DIM * S_DIM * DH +
                           (size_t)(s0 + l16) * DH + quad * 8;
      const float* lp = lsum + (size_t)b * H_DIM * T_DIM + tw + l16;

      for (int h = 0; h < H_DIM; ++h) {
        half8 qfrag = *(const half8*)qp;
        float rlv = 0.125f / *lp;
#pragma unroll
        for (int st = 0; st < 8; ++st) {
          half8 kfr = *(const half8*)(kp + st * 512);
          floatx4 c = {0.f, 0.f, 0.f, 0.f};
          c = __builtin_amdgcn_mfma_f32_16x16x32_f16(kfr, qfrag, c, 0, 0, 0);  // S^T
#pragma unroll
          for (int r = 0; r < 4; ++r) acc[st][r] += EXPFN(c[r]) * rlv;
        }
        qp += (size_t)T_DIM * DH;
        kp += (size_t)S_DIM * DH;
        lp += T_DIM;
      }
#pragma unroll
      for (int st = 0; st < 8; ++st)
        *(floatx4*)&smemf[(w * 16 + l16) * ASTRIDE + st * 16 + quad * 4] = acc[st];
      __syncthreads();

      int rbase = tid >> 4, seg = tid & 15;
#pragma unroll
      for (int rr = 0; rr < 4; ++rr) {
        int row = rr * 32 + rbase;
        const float* srcl = &smemf[row * ASTRIDE];
        float* dst = avg_out + ((size_t)b * T_DIM + t0 + row) * S_DIM + s0;
#pragma unroll
        for (int k = 0; k < 2; ++k) {
          int col = seg * 4 + k * 64;
          *(floatx4*)(dst + col) = *(const floatx4*)(srcl + col);
        }
      }
      __syncthreads();  // protect smemf for next unit
    }

    // outproj: one 64r x 64c tile per block; 64 r-blocks x 4 c-blocks = 256
    // units (full 4096 rows). 8 waves: wave w -> row-subtile (w&3)*16,
    // col-pair (w>>2)*32 + {0,16}; K=256 via 8 k-steps x 2 MFMAs.
    int r0o = (bx >> 2) * 64, c0o = (bx & 3) * 64;
    _Float16* Ws = (_Float16*)smem_raw;  // 64 x XS halves
#pragma unroll
    for (int it = 0; it < 8; ++it) {
      int row = (tid >> 6) + it * 8, col = (tid & 63) * 4;
      int f = c0o + row;
      float4 a = *(const float4*)(Wo + (size_t)f * 256 + col);
      half4 hv;
      hv[0] = (_Float16)a.x; hv[1] = (_Float16)a.y;
      hv[2] = (_Float16)a.z; hv[3] = (_Float16)a.w;
      int di = f - col;
      if (di >= 0 && di < 4) hv[di] += (_Float16)1.0f;  // fold +I
      *(half4*)(Ws + row * XS + col) = hv;
    }
    __syncthreads();

    int rsel = w & 3, csel = w >> 2;
    floatx4 c0acc = {0.f, 0.f, 0.f, 0.f};
    floatx4 c1acc = {0.f, 0.f, 0.f, 0.f};
    int grow = r0o + rsel * 16 + l16;
    const _Float16* Arow = Of16 + (size_t)grow * 256 + quad * 8;
    const _Float16* Wsrow0 = Ws + (size_t)(csel * 32 + l16) * XS + quad * 8;
    const _Float16* Wsrow1 = Wsrow0 + 16 * XS;
#pragma unroll 2
    for (int k0 = 0; k0 < 256; k0 += 32) {
      half8 af = *(const half8*)(Arow + k0);
      half8 bf0 = *(const half8*)(Wsrow0 + k0);
      half8 bf1 = *(const half8*)(Wsrow1 + k0);
      c0acc = __builtin_amdgcn_mfma_f32_16x16x32_f16(af, bf0, c0acc, 0, 0, 0);
      c1acc = __builtin_amdgcn_mfma_f32_16x16x32_f16(af, bf1, c1acc, 0, 0, 0);
    }
    int f0 = c0o + csel * 32 + l16;
    float bv0 = bo[f0], bv1 = bo[f0 + 16];
#pragma unroll
    for (int r = 0; r < 4; ++r) {
      int row = r0o + rsel * 16 + quad * 4 + r;
      out[(size_t)row * 256 + f0] = c0acc[r] + bv0;
      out[(size_t)row * 256 + f0 + 16] = c1acc[r] + bv1;
    }
  }
}

// ===========================================================================
// Fallback path: the verified r3 three-kernel pipeline (used only if the
// cooperative launch is rejected by the runtime/graph-capture).
// ===========================================================================
__global__ __launch_bounds__(256, 4) void k1_proj_vt(
    const float* __restrict__ Q, const float* __restrict__ K,
    const float* __restrict__ V,
    const float* __restrict__ Wq, const float* __restrict__ Wk,
    const float* __restrict__ bq, const float* __restrict__ bk,
    _Float16* __restrict__ Qp, _Float16* __restrict__ Kp,
    _Float16* __restrict__ Vt2, float scale_q) {
  __shared__ __align__(16) _Float16 smem[64 * XS];
  int tid = threadIdx.x;
  int bx = blockIdx.x;
  if (bx < 512) {
    int z = bx >> 8;
    int rem = bx & 255;
    int r0 = (rem >> 2) * 64;
    int c0 = (rem & 3) * 64;
    const float* X = z ? K : Q;
    const float* W = z ? Wk : Wq;
    const float* bias = z ? bk : bq;
    _Float16* outp = z ? Kp : Qp;
    float scale = z ? 1.0f : scale_q;
    _Float16* Xs = smem;
    int lane = tid & 63, w = tid >> 6;
    int quad = lane >> 4, l16 = lane & 15;
#pragma unroll
    for (int it = 0; it < 16; ++it) {
      int row = (tid >> 6) + it * 4, col = (tid & 63) * 4;
      float4 a = *(const float4*)(X + (size_t)(r0 + row) * 256 + col);
      half4 hx;
      hx[0] = (_Float16)a.x; hx[1] = (_Float16)a.y;
      hx[2] = (_Float16)a.z; hx[3] = (_Float16)a.w;
      *(half4*)(Xs + row * XS + col) = hx;
    }
    __syncthreads();
    floatx4 c[4] = {{0.f,0.f,0.f,0.f},{0.f,0.f,0.f,0.f},{0.f,0.f,0.f,0.f},{0.f,0.f,0.f,0.f}};
    int arow = w * 16 + l16;
    const float* Wr0 = W + (size_t)(c0 + l16) * 256 + quad * 8;
#pragma unroll 2
    for (int k0 = 0; k0 < 256; k0 += 32) {
      half8 af = *(const half8*)(Xs + arow * XS + k0 + quad * 8);
#pragma unroll
      for (int j = 0; j < 4; ++j) {
        const float* Wr = Wr0 + j * 16 * 256 + k0;
        float4 w0 = *(const float4*)(Wr);
        float4 w1 = *(const float4*)(Wr + 4);
        half8 bf;
        bf[0] = (_Float16)w0.x; bf[1] = (_Float16)w0.y;
        bf[2] = (_Float16)w0.z; bf[3] = (_Float16)w0.w;
        bf[4] = (_Float16)w1.x; bf[5] = (_Float16)w1.y;
        bf[6] = (_Float16)w1.z; bf[7] = (_Float16)w1.w;
        c[j] = __builtin_amdgcn_mfma_f32_16x16x32_f16(af, bf, c[j], 0, 0, 0);
      }
    }
#pragma unroll
    for (int j = 0; j < 4; ++j) {
      int f = c0 + j * 16 + l16;
      float bv = bias[f];
      int h = f >> 5, d = f & 31;
#pragma unroll
      for (int r = 0; r < 4; ++r) {
        int row = r0 + w * 16 + quad * 4 + r;
        int t = row >> 1, b = row & 1;
        outp[(((size_t)b * H_DIM + h) * T_DIM + t) * DH + d] =
            (_Float16)((c[j][r] + bv) * scale);
      }
    }
  } else {
    float (*tile)[33] = (float (*)[33])smem;
    int b2 = bx - 512;
    int st = b2 & 31, h = (b2 >> 5) & 7, b = b2 >> 8;
    int s0 = st * 64;
    int d = tid & 31, sr = tid >> 5;
#pragma unroll
    for (int k = 0; k < 8; ++k) {
      int s = sr + k * 8;
      tile[s][d] = V[((size_t)(s0 + s) * B_DIM + b) * E_DIM + h * DH + d];
    }
    __syncthreads();
    int si = tid & 63, dq = tid >> 6;
    size_t base = ((size_t)b * H_DIM + h) * 128 * 512;
    int tl = st * 4 + (si >> 4);
    int sl = si & 15;
#pragma unroll
    for (int m = 0; m < 8; ++m) {
      int dd = dq * 8 + m;
      Vt2[base + (size_t)tl * 512 + dd * 16 + sl] = (_Float16)tile[si][dd];
    }
  }
}

__global__ __launch_bounds__(512, 2) void attn_o_kernel(const _Float16* __restrict__ Qp,
                                                        const _Float16* __restrict__ Kp,
                                                        const _Float16* __restrict__ Vt2,
                                                        _Float16* __restrict__ Of16,
                                                        float* __restrict__ lsum) {
  __shared__ float stageO[8][64 * OSTRIDE];
  __shared__ float lstage[8][64];
  int tid = threadIdx.x;
  int lane = tid & 63, w = tid >> 6;
  int quad = lane >> 4, l16 = lane & 15;
  int bx = blockIdx.x;
  int h = bx & 7, b = (bx >> 3) & 1, tcc = bx >> 4;
  int t0 = tcc << 6;
  const _Float16* Qb = Qp + (((size_t)b * H_DIM + h) * T_DIM + t0) * DH;
  half8 qf[4];
#pragma unroll
  for (int j = 0; j < 4; ++j)
    qf[j] = *(const half8*)(Qb + (size_t)(j * 16 + l16) * DH + quad * 8);
  floatx4 o[4][2];
#pragma unroll
  for (int j = 0; j < 4; ++j) { o[j][0] = (floatx4){0,0,0,0}; o[j][1] = (floatx4){0,0,0,0}; }
  float ls[4] = {0.f, 0.f, 0.f, 0.f};
  int tile0 = w * 16;
  const _Float16* kp = Kp + ((size_t)b * H_DIM + h) * S_DIM * DH +
                       (size_t)(tile0 * 16 + l16) * DH + quad * 8;
  const _Float16* vp = Vt2 + ((size_t)b * H_DIM + h) * 128 * 512 +
                       (size_t)tile0 * 512 + l16 * 16 + quad * 4;
  half8 kf[2];
  half4 v0[2], v1[2];
  kf[0] = *(const half8*)kp;
  v0[0] = *(const half4*)vp;
  v1[0] = *(const half4*)(vp + 256);
  kp += 512; vp += 512;
  for (int ii = 0; ii < 7; ++ii) {
    ATTN_STEP(0, 1, true);
    ATTN_STEP(1, 0, true);
  }
  ATTN_STEP(0, 1, true);
  ATTN_STEP(1, 0, false);
#pragma unroll
  for (int j = 0; j < 4; ++j) {
    float v = ls[j];
    v += __shfl_xor(v, 16, 64);
    v += __shfl_xor(v, 32, 64);
    if (quad == 0) lstage[w][j * 16 + l16] = v;
  }
#pragma unroll
  for (int j = 0; j < 4; ++j)
#pragma unroll
    for (int r = 0; r < 4; ++r) {
      stageO[w][(j * 16 + quad * 4 + r) * OSTRIDE + l16] = o[j][0][r];
      stageO[w][(j * 16 + quad * 4 + r) * OSTRIDE + 16 + l16] = o[j][1][r];
    }
  __syncthreads();
  int t = tid >> 3, d0 = (tid & 7) * 4;
  floatx4 os = {0.f, 0.f, 0.f, 0.f};
  float lr = 0.f;
#pragma unroll
  for (int ww = 0; ww < 8; ++ww) {
    os += *(const floatx4*)&stageO[ww][t * OSTRIDE + d0];
    lr += lstage[ww][t];
  }
  float rl = 1.0f / lr;
  half4 oh;
  oh[0] = (_Float16)(os[0] * rl); oh[1] = (_Float16)(os[1] * rl);
  oh[2] = (_Float16)(os[2] * rl); oh[3] = (_Float16)(os[3] * rl);
  *(half4*)(Of16 + ((size_t)(t0 + t) * B_DIM + b) * E_DIM + h * DH + d0) = oh;
  if (tid < 64) {
    float s = 0.f;
#pragma unroll
    for (int ww = 0; ww < 8; ++ww) s += lstage[ww][tid];
    lsum[((size_t)b * H_DIM + h) * T_DIM + t0 + tid] = s;
  }
}

__global__ __launch_bounds__(512, 2) void k3_avg_outproj(
    const _Float16* __restrict__ Qp, const _Float16* __restrict__ Kp,
    const float* __restrict__ lsum, const _Float16* __restrict__ Of16,
    const float* __restrict__ Wo, const float* __restrict__ bo,
    float* __restrict__ avg_out, float* __restrict__ out) {
  __shared__ __align__(16) float smem[128 * ASTRIDE];
  int tid = threadIdx.x;
  int lane = tid & 63, w = tid >> 6;
  int quad = lane >> 4, l16 = lane & 15;
  int bx = blockIdx.x;
  if (bx < 512) {
    int sc = bx & 15, tc = (bx >> 4) & 15, b = bx >> 8;
    int t0 = tc * 128, s0 = sc * 128;
    int tw = t0 + w * 16;
    floatx4 acc[8];
#pragma unroll
    for (int st = 0; st < 8; ++st) acc[st] = (floatx4){0.f, 0.f, 0.f, 0.f};
    const _Float16* qp = Qp + (size_t)b * H_DIM * T_DIM * DH +
                         (size_t)(tw + l16) * DH + quad * 8;
    const _Float16* kp = Kp + (size_t)b * H_DIM * S_DIM * DH +
                         (size_t)(s0 + l16) * DH + quad * 8;
    const float* lp = lsum + (size_t)b * H_DIM * T_DIM + tw + l16;
    for (int h = 0; h < H_DIM; ++h) {
      half8 qfrag = *(const half8*)qp;
      float rlv = 0.125f / *lp;
#pragma unroll
      for (int st = 0; st < 8; ++st) {
        half8 kfr = *(const half8*)(kp + st * 512);
        floatx4 c = {0.f, 0.f, 0.f, 0.f};
        c = __builtin_amdgcn_mfma_f32_16x16x32_f16(kfr, qfrag, c, 0, 0, 0);
#pragma unroll
        for (int r = 0; r < 4; ++r) acc[st][r] += EXPFN(c[r]) * rlv;
      }
      qp += (size_t)T_DIM * DH;
      kp += (size_t)S_DIM * DH;
      lp += T_DIM;
    }
#pragma unroll
    for (int st = 0; st < 8; ++st)
      *(floatx4*)&smem[(w * 16 + l16) * ASTRIDE + st * 16 + quad * 4] = acc[st];
    __syncthreads();
    int rbase = tid >> 4, seg = tid & 15;
#pragma unroll
    for (int rr = 0; rr < 4; ++rr) {
      int row = rr * 32 + rbase;
      const float* srcl = &smem[row * ASTRIDE];
      float* dst = avg_out + ((size_t)b * T_DIM + t0 + row) * S_DIM + s0;
#pragma unroll
      for (int k = 0; k < 2; ++k) {
        int col = seg * 4 + k * 64;
        *(floatx4*)(dst + col) = *(const floatx4*)(srcl + col);
      }
    }
  } else {
    int bo_ = bx - 512;
    int r0 = (bo_ >> 2) * 128;
    int c0 = (bo_ & 3) * 64;
    _Float16* Ws = (_Float16*)smem;
#pragma unroll
    for (int it = 0; it < 8; ++it) {
      int row = (tid >> 6) + it * 8, col = (tid & 63) * 4;
      int f = c0 + row;
      float4 a = *(const float4*)(Wo + (size_t)f * 256 + col);
      half4 hv;
      hv[0] = (_Float16)a.x; hv[1] = (_Float16)a.y;
      hv[2] = (_Float16)a.z; hv[3] = (_Float16)a.w;
      int di = f - col;
      if (di >= 0 && di < 4) hv[di] += (_Float16)1.0f;
      *(half4*)(Ws + row * XS + col) = hv;
    }
    __syncthreads();
    floatx4 c[4] = {{0.f,0.f,0.f,0.f},{0.f,0.f,0.f,0.f},{0.f,0.f,0.f,0.f},{0.f,0.f,0.f,0.f}};
    int grow = r0 + w * 16 + l16;
#pragma unroll 2
    for (int k0 = 0; k0 < 256; k0 += 32) {
      half8 af = *(const half8*)(Of16 + (size_t)grow * 256 + k0 + quad * 8);
#pragma unroll
      for (int j = 0; j < 4; ++j) {
        half8 bf = *(const half8*)(Ws + (j * 16 + l16) * XS + k0 + quad * 8);
        c[j] = __builtin_amdgcn_mfma_f32_16x16x32_f16(af, bf, c[j], 0, 0, 0);
      }
    }
#pragma unroll
    for (int j = 0; j < 4; ++j) {
      int f = c0 + j * 16 + l16;
      float bv = bo[f];
#pragma unroll
      for (int r = 0; r < 4; ++r) {
        int row = r0 + w * 16 + quad * 4 + r;
        out[(size_t)row * 256 + f] = c[j][r] + bv;
      }
    }
  }
}

// ---------------------------------------------------------------------------
extern "C" void kernel_launch(void* const* d_in, const int* in_sizes, int n_in,
                              void* d_out, int out_size, void* d_ws, size_t ws_size,
                              hipStream_t stream) {
  const float* query = (const float*)d_in[0];
  const float* key   = (const float*)d_in[1];
  const float* value = (const float*)d_in[2];
  const float* Wq    = (const float*)d_in[3];
  const float* bq    = (const float*)d_in[4];
  const float* Wk    = (const float*)d_in[5];
  const float* bk    = (const float*)d_in[6];
  const float* Wo    = (const float*)d_in[7];
  const float* bo    = (const float*)d_in[8];

  float* out = (float*)d_out;
  float* avg_out = out + (size_t)T_DIM * B_DIM * E_DIM;

  char* ws = (char*)d_ws;
  _Float16* Qp   = (_Float16*)ws;                       // 2 MB
  _Float16* Kp   = (_Float16*)(ws + (2u << 20));        // 2 MB
  _Float16* Vt2  = (_Float16*)(ws + (4u << 20));        // 2 MB
  _Float16* Of16 = (_Float16*)(ws + (6u << 20));        // 2 MB
  float*    lsum = (float*)(ws + (8u << 20));           // 128 KB

  float scale_q = 0.17677669529663687f * LOG2E_FOLD;

  void* kargs[] = {(void*)&query, (void*)&key, (void*)&value,
                   (void*)&Wq, (void*)&Wk, (void*)&bq, (void*)&bk,
                   (void*)&Wo, (void*)&bo,
                   (void*)&Qp, (void*)&Kp, (void*)&Vt2, (void*)&Of16,
                   (void*)&lsum, (void*)&out, (void*)&avg_out,
                   (void*)&scale_q};
  hipError_t err = hipLaunchCooperativeKernel((const void*)fused_all, dim3(256),
                                              dim3(512), kargs, 0, stream);
  if (err != hipSuccess) {
    // fallback: verified r3 three-kernel pipeline
    k1_proj_vt<<<dim3(1024), dim3(256), 0, stream>>>(query, key, value, Wq, Wk,
                                                     bq, bk, Qp, Kp, Vt2, scale_q);
    attn_o_kernel<<<dim3(512), dim3(512), 0, stream>>>(Qp, Kp, Vt2, Of16, lsum);
    k3_avg_outproj<<<dim3(640), dim3(512), 0, stream>>>(Qp, Kp, lsum, Of16, Wo, bo,
                                                        avg_out, out);
  }
}

// Round 7
// 140.474 us; speedup vs baseline: 1.6833x; 1.6833x over previous
//
#include <hip/hip_runtime.h>
#include <hip/hip_fp16.h>

#define T_DIM 2048
#define S_DIM 2048
#define B_DIM 2
#define E_DIM 256
#define H_DIM 8
#define DH 32

typedef _Float16 half8 __attribute__((ext_vector_type(8)));
typedef _Float16 half4 __attribute__((ext_vector_type(4)));
typedef __fp16 fp16x2 __attribute__((ext_vector_type(2)));
typedef float floatx4 __attribute__((ext_vector_type(4)));

// v_exp_f32 computes 2^x. Fold log2(e) into the Q scale so exp(s) == exp2(s').
#if defined(__has_builtin)
#if __has_builtin(__builtin_amdgcn_exp2f)
#define EXPFN(x) __builtin_amdgcn_exp2f(x)
#define LOG2E_FOLD 1.4426950408889634f
#endif
#if __has_builtin(__builtin_amdgcn_cvt_pkrtz)
#define HAVE_PKRTZ 1
#endif
#endif
#ifndef EXPFN
#define EXPFN(x) __expf(x)
#define LOG2E_FOLD 1.0f
#endif

// pack 4 f32 -> half4 (v_cvt_pkrtz_f16_f32 x2 when available; RTZ bias
// cancels in softmax since the denominator sums the same fp16 values).
// NOTE: the builtin returns __fp16 ext_vector(2); union member must match
// (r6 compile fail). __fp16/_Float16 are bit-identical fp16 on gfx950.
__device__ __forceinline__ half4 pk4(float e0, float e1, float e2, float e3) {
#ifdef HAVE_PKRTZ
  union { fp16x2 h2[2]; half4 h4; } u;
  u.h2[0] = __builtin_amdgcn_cvt_pkrtz(e0, e1);
  u.h2[1] = __builtin_amdgcn_cvt_pkrtz(e2, e3);
  return u.h4;
#else
  half4 p;
  p[0] = (_Float16)e0; p[1] = (_Float16)e1;
  p[2] = (_Float16)e2; p[3] = (_Float16)e3;
  return p;
#endif
}

#define XS 264  // 256 + 8 halves pad

// ---------------------------------------------------------------------------
// K1 (fat): bx<512 -> Q/K projection. X staged fp32->fp16 in LDS (33.8 KB ->
//           4 blocks/CU); W converted inline fp32->fp16 in registers (L2-hot).
//           bx>=512 -> V transpose to Vt2.  (verified r3 structure)
// ---------------------------------------------------------------------------
__global__ __launch_bounds__(256, 4) void k1_proj_vt(
    const float* __restrict__ Q, const float* __restrict__ K,
    const float* __restrict__ V,
    const float* __restrict__ Wq, const float* __restrict__ Wk,
    const float* __restrict__ bq, const float* __restrict__ bk,
    _Float16* __restrict__ Qp, _Float16* __restrict__ Kp,
    _Float16* __restrict__ Vt2, float scale_q) {
  __shared__ __align__(16) _Float16 smem[64 * XS];  // 33.8 KB
  int tid = threadIdx.x;
  int bx = blockIdx.x;
  if (bx < 512) {
    // ---- projection: block = 64r x 64c, 4 waves ----
    int z = bx >> 8;  // 0: Q, 1: K
    int rem = bx & 255;
    int r0 = (rem >> 2) * 64;
    int c0 = (rem & 3) * 64;
    const float* X = z ? K : Q;
    const float* W = z ? Wk : Wq;
    const float* bias = z ? bk : bq;
    _Float16* outp = z ? Kp : Qp;
    float scale = z ? 1.0f : scale_q;
    _Float16* Xs = smem;
    int lane = tid & 63, w = tid >> 6;
    int quad = lane >> 4, l16 = lane & 15;
    // stage X rows [r0,r0+64), fp32 -> fp16
#pragma unroll
    for (int it = 0; it < 16; ++it) {
      int row = (tid >> 6) + it * 4, col = (tid & 63) * 4;
      float4 a = *(const float4*)(X + (size_t)(r0 + row) * 256 + col);
      half4 hx;
      hx[0] = (_Float16)a.x; hx[1] = (_Float16)a.y;
      hx[2] = (_Float16)a.z; hx[3] = (_Float16)a.w;
      *(half4*)(Xs + row * XS + col) = hx;
    }
    __syncthreads();

    floatx4 c[4] = {{0.f,0.f,0.f,0.f},{0.f,0.f,0.f,0.f},{0.f,0.f,0.f,0.f},{0.f,0.f,0.f,0.f}};
    int arow = w * 16 + l16;
    const float* Wr0 = W + (size_t)(c0 + l16) * 256 + quad * 8;
#pragma unroll 2
    for (int k0 = 0; k0 < 256; k0 += 32) {
      half8 af = *(const half8*)(Xs + arow * XS + k0 + quad * 8);
#pragma unroll
      for (int j = 0; j < 4; ++j) {
        const float* Wr = Wr0 + j * 16 * 256 + k0;
        float4 w0 = *(const float4*)(Wr);
        float4 w1 = *(const float4*)(Wr + 4);
        half8 bf;
        bf[0] = (_Float16)w0.x; bf[1] = (_Float16)w0.y;
        bf[2] = (_Float16)w0.z; bf[3] = (_Float16)w0.w;
        bf[4] = (_Float16)w1.x; bf[5] = (_Float16)w1.y;
        bf[6] = (_Float16)w1.z; bf[7] = (_Float16)w1.w;
        c[j] = __builtin_amdgcn_mfma_f32_16x16x32_f16(af, bf, c[j], 0, 0, 0);
      }
    }
#pragma unroll
    for (int j = 0; j < 4; ++j) {
      int f = c0 + j * 16 + l16;
      float bv = bias[f];
      int h = f >> 5, d = f & 31;
#pragma unroll
      for (int r = 0; r < 4; ++r) {
        int row = r0 + w * 16 + quad * 4 + r;
        int t = row >> 1, b = row & 1;
        outp[(((size_t)b * H_DIM + h) * T_DIM + t) * DH + d] =
            (_Float16)((c[j][r] + bv) * scale);
      }
    }
  } else {
    // ---- V transpose: Vt2[b,h,tile=s>>4][d][s&15] ----
    float (*tile)[33] = (float (*)[33])smem;  // 8.4 KB of the union
    int b2 = bx - 512;
    int st = b2 & 31, h = (b2 >> 5) & 7, b = b2 >> 8;
    int s0 = st * 64;
    int d = tid & 31, sr = tid >> 5;
#pragma unroll
    for (int k = 0; k < 8; ++k) {
      int s = sr + k * 8;
      tile[s][d] = V[((size_t)(s0 + s) * B_DIM + b) * E_DIM + h * DH + d];
    }
    __syncthreads();
    int si = tid & 63, dq = tid >> 6;
    size_t base = ((size_t)b * H_DIM + h) * 128 * 512;
    int tl = st * 4 + (si >> 4);
    int sl = si & 15;
#pragma unroll
    for (int m = 0; m < 8; ++m) {
      int dd = dq * 8 + m;
      Vt2[base + (size_t)tl * 512 + dd * 16 + sl] = (_Float16)tile[si][dd];
    }
  }
}

// ---------------------------------------------------------------------------
// attn_o: block = (b,h,64-t), 8 waves; wave holds 4 Q-frags, owns 16 s-tiles.
// XCD swizzle: h == bx%8 == XCD -> one head's K/V L2-resident per XCD.
// VALU-cut: (a) lsum via ones-column MFMA (ol[j] = mfma(p, 1, ol[j]): every B
// element == 1 so D rows are exact P-row-sums, layout-independent) -- removes
// 4 adds/j-iter + the end shuffles, moving work to the underused MFMA pipe;
// (b) p packed with v_cvt_pkrtz (2 instr vs 4 cvt + packs).
// ---------------------------------------------------------------------------
#define OSTRIDE 36

#define ATTN_STEP(cur, nxt, PRE)                                                \
  {                                                                             \
    if (PRE) {                                                                  \
      kf[nxt] = *(const half8*)kp;                                              \
      v0[nxt] = *(const half4*)vp;                                              \
      v1[nxt] = *(const half4*)(vp + 256);                                      \
      kp += 512; vp += 512;                                                     \
    }                                                                           \
    _Pragma("unroll")                                                           \
    for (int j = 0; j < 4; ++j) {                                               \
      floatx4 c = {0.f, 0.f, 0.f, 0.f};                                         \
      c = __builtin_amdgcn_mfma_f32_16x16x32_f16(kf[cur], qf[j], c, 0, 0, 0);   \
      half4 p = pk4(EXPFN(c[0]), EXPFN(c[1]), EXPFN(c[2]), EXPFN(c[3]));        \
      o[j][0] = __builtin_amdgcn_mfma_f32_16x16x16f16(p, v0[cur], o[j][0], 0, 0, 0); \
      o[j][1] = __builtin_amdgcn_mfma_f32_16x16x16f16(p, v1[cur], o[j][1], 0, 0, 0); \
      ol[j]   = __builtin_amdgcn_mfma_f32_16x16x16f16(p, vone,    ol[j],   0, 0, 0); \
    }                                                                           \
  }

__global__ __launch_bounds__(512, 4) void attn_o_kernel(const _Float16* __restrict__ Qp,
                                                        const _Float16* __restrict__ Kp,
                                                        const _Float16* __restrict__ Vt2,
                                                        _Float16* __restrict__ Of16,
                                                        float* __restrict__ lsum) {
  __shared__ float stageO[8][64 * OSTRIDE];  // 72 KB
  __shared__ float lstage[8][64];

  int tid = threadIdx.x;
  int lane = tid & 63, w = tid >> 6;
  int quad = lane >> 4, l16 = lane & 15;
  int bx = blockIdx.x;
  int h = bx & 7, b = (bx >> 3) & 1, tcc = bx >> 4;
  int t0 = tcc << 6;

  const _Float16* Qb = Qp + (((size_t)b * H_DIM + h) * T_DIM + t0) * DH;

  half8 qf[4];
#pragma unroll
  for (int j = 0; j < 4; ++j)
    qf[j] = *(const half8*)(Qb + (size_t)(j * 16 + l16) * DH + quad * 8);

  floatx4 o[4][2];
  floatx4 ol[4];
#pragma unroll
  for (int j = 0; j < 4; ++j) {
    o[j][0] = (floatx4){0,0,0,0};
    o[j][1] = (floatx4){0,0,0,0};
    ol[j]   = (floatx4){0,0,0,0};
  }
  const half4 vone = {(_Float16)1.0f, (_Float16)1.0f, (_Float16)1.0f, (_Float16)1.0f};

  int tile0 = w * 16;
  // incremental pointers; both advance by 512 halfs (1 KB) per s-tile
  const _Float16* kp = Kp + ((size_t)b * H_DIM + h) * S_DIM * DH +
                       (size_t)(tile0 * 16 + l16) * DH + quad * 8;
  const _Float16* vp = Vt2 + ((size_t)b * H_DIM + h) * 128 * 512 +
                       (size_t)tile0 * 512 + l16 * 16 + quad * 4;

  half8 kf[2];
  half4 v0[2], v1[2];
  kf[0] = *(const half8*)kp;
  v0[0] = *(const half4*)vp;
  v1[0] = *(const half4*)(vp + 256);
  kp += 512; vp += 512;

  for (int ii = 0; ii < 7; ++ii) {  // 14 tiles, rolled (7x2 for static dbuf idx)
    ATTN_STEP(0, 1, true);
    ATTN_STEP(1, 0, true);
  }
  ATTN_STEP(0, 1, true);   // tile 14, prefetch tile 15
  ATTN_STEP(1, 0, false);  // tile 15, no prefetch

  // lsum rows live in ol[j][r] at t = j*16 + quad*4 + r, identical on all
  // 16 cols; lanes with l16==0 publish them.
  if (l16 == 0) {
#pragma unroll
    for (int j = 0; j < 4; ++j)
#pragma unroll
      for (int r = 0; r < 4; ++r)
        lstage[w][j * 16 + quad * 4 + r] = ol[j][r];
  }
#pragma unroll
  for (int j = 0; j < 4; ++j)
#pragma unroll
    for (int r = 0; r < 4; ++r) {
      stageO[w][(j * 16 + quad * 4 + r) * OSTRIDE + l16] = o[j][0][r];
      stageO[w][(j * 16 + quad * 4 + r) * OSTRIDE + 16 + l16] = o[j][1][r];
    }
  __syncthreads();

  int t = tid >> 3, d0 = (tid & 7) * 4;
  floatx4 os = {0.f, 0.f, 0.f, 0.f};
  float lr = 0.f;
#pragma unroll
  for (int ww = 0; ww < 8; ++ww) {
    os += *(const floatx4*)&stageO[ww][t * OSTRIDE + d0];
    lr += lstage[ww][t];
  }
  float rl = 1.0f / lr;
  half4 oh;
  oh[0] = (_Float16)(os[0] * rl); oh[1] = (_Float16)(os[1] * rl);
  oh[2] = (_Float16)(os[2] * rl); oh[3] = (_Float16)(os[3] * rl);
  *(half4*)(Of16 + ((size_t)(t0 + t) * B_DIM + b) * E_DIM + h * DH + d0) = oh;
  if (tid < 64) {
    float s = 0.f;
#pragma unroll
    for (int ww = 0; ww < 8; ++ww) s += lstage[ww][tid];
    lsum[((size_t)b * H_DIM + h) * T_DIM + t0 + tid] = s;
  }
}

// ---------------------------------------------------------------------------
// K3 (fat): bx<512 -> avg (recompute scores, 128t x 128s, XCD swizzle on sc);
//           bx>=512 -> outproj GEMM. Incremental per-h pointers; st-loop kept
//           fully unrolled (acc[] must stay statically indexed). (512,4) =
//           cap 128, 2 blocks/CU.  (verified r3 structure)
// ---------------------------------------------------------------------------
#define ASTRIDE 132
__global__ __launch_bounds__(512, 4) void k3_avg_outproj(
    const _Float16* __restrict__ Qp, const _Float16* __restrict__ Kp,
    const float* __restrict__ lsum, const _Float16* __restrict__ Of16,
    const float* __restrict__ Wo, const float* __restrict__ bo,
    float* __restrict__ avg_out, float* __restrict__ out) {
  __shared__ __align__(16) float smem[128 * ASTRIDE];  // 67.6 KB (union)
  int tid = threadIdx.x;
  int lane = tid & 63, w = tid >> 6;
  int quad = lane >> 4, l16 = lane & 15;
  int bx = blockIdx.x;

  if (bx < 512) {
    // ---- avg ----
    int sc = bx & 15, tc = (bx >> 4) & 15, b = bx >> 8;
    int t0 = tc * 128, s0 = sc * 128;
    int tw = t0 + w * 16;

    floatx4 acc[8];
#pragma unroll
    for (int st = 0; st < 8; ++st) acc[st] = (floatx4){0.f, 0.f, 0.f, 0.f};

    // incremental per-h pointers (stride T*DH = 65536 halfs)
    const _Float16* qp = Qp + (size_t)b * H_DIM * T_DIM * DH +
                         (size_t)(tw + l16) * DH + quad * 8;
    const _Float16* kp = Kp + (size_t)b * H_DIM * S_DIM * DH +
                         (size_t)(s0 + l16) * DH + quad * 8;
    const float* lp = lsum + (size_t)b * H_DIM * T_DIM + tw + l16;

    for (int h = 0; h < H_DIM; ++h) {
      half8 qfrag = *(const half8*)qp;
      float rlv = 0.125f / *lp;
#pragma unroll
      for (int st = 0; st < 8; ++st) {
        half8 kfr = *(const half8*)(kp + st * 512);
        floatx4 c = {0.f, 0.f, 0.f, 0.f};
        c = __builtin_amdgcn_mfma_f32_16x16x32_f16(kfr, qfrag, c, 0, 0, 0);  // S^T
#pragma unroll
        for (int r = 0; r < 4; ++r) acc[st][r] += EXPFN(c[r]) * rlv;
      }
      qp += (size_t)T_DIM * DH;
      kp += (size_t)S_DIM * DH;
      lp += T_DIM;
    }
#pragma unroll
    for (int st = 0; st < 8; ++st)
      *(floatx4*)&smem[(w * 16 + l16) * ASTRIDE + st * 16 + quad * 4] = acc[st];
    __syncthreads();

    int rbase = tid >> 4, seg = tid & 15;
#pragma unroll
    for (int rr = 0; rr < 4; ++rr) {
      int row = rr * 32 + rbase;
      const float* srcl = &smem[row * ASTRIDE];
      float* dst = avg_out + ((size_t)b * T_DIM + t0 + row) * S_DIM + s0;
#pragma unroll
      for (int k = 0; k < 2; ++k) {
        int col = seg * 4 + k * 64;
        *(floatx4*)(dst + col) = *(const floatx4*)(srcl + col);
      }
    }
  } else {
    // ---- outproj: block = 128r x 64c, 8 waves ----
    int bo_ = bx - 512;               // 0..127
    int r0 = (bo_ >> 2) * 128;
    int c0 = (bo_ & 3) * 64;
    _Float16* Ws = (_Float16*)smem;   // 64 x XS halves (33.8 KB)
    // stage (Wo + I) rows [c0,c0+64), fp32 -> fp16, fold +I during staging
#pragma unroll
    for (int it = 0; it < 8; ++it) {
      int row = (tid >> 6) + it * 8, col = (tid & 63) * 4;
      int f = c0 + row;
      float4 a = *(const float4*)(Wo + (size_t)f * 256 + col);
      half4 hv;
      hv[0] = (_Float16)a.x; hv[1] = (_Float16)a.y;
      hv[2] = (_Float16)a.z; hv[3] = (_Float16)a.w;
      int di = f - col;
      if (di >= 0 && di < 4) hv[di] += (_Float16)1.0f;
      *(half4*)(Ws + row * XS + col) = hv;
    }
    __syncthreads();

    floatx4 c[4] = {{0.f,0.f,0.f,0.f},{0.f,0.f,0.f,0.f},{0.f,0.f,0.f,0.f},{0.f,0.f,0.f,0.f}};
    int grow = r0 + w * 16 + l16;
#pragma unroll 2
    for (int k0 = 0; k0 < 256; k0 += 32) {
      half8 af = *(const half8*)(Of16 + (size_t)grow * 256 + k0 + quad * 8);
#pragma unroll
      for (int j = 0; j < 4; ++j) {
        half8 bf = *(const half8*)(Ws + (j * 16 + l16) * XS + k0 + quad * 8);
        c[j] = __builtin_amdgcn_mfma_f32_16x16x32_f16(af, bf, c[j], 0, 0, 0);
      }
    }
#pragma unroll
    for (int j = 0; j < 4; ++j) {
      int f = c0 + j * 16 + l16;
      float bv = bo[f];
#pragma unroll
      for (int r = 0; r < 4; ++r) {
        int row = r0 + w * 16 + quad * 4 + r;
        out[(size_t)row * 256 + f] = c[j][r] + bv;
      }
    }
  }
}

// ---------------------------------------------------------------------------
extern "C" void kernel_launch(void* const* d_in, const int* in_sizes, int n_in,
                              void* d_out, int out_size, void* d_ws, size_t ws_size,
                              hipStream_t stream) {
  const float* query = (const float*)d_in[0];
  const float* key   = (const float*)d_in[1];
  const float* value = (const float*)d_in[2];
  const float* Wq    = (const float*)d_in[3];
  const float* bq    = (const float*)d_in[4];
  const float* Wk    = (const float*)d_in[5];
  const float* bk    = (const float*)d_in[6];
  const float* Wo    = (const float*)d_in[7];
  const float* bo    = (const float*)d_in[8];

  float* out = (float*)d_out;
  float* avg_out = out + (size_t)T_DIM * B_DIM * E_DIM;

  char* ws = (char*)d_ws;
  _Float16* Qp   = (_Float16*)ws;                       // 2 MB
  _Float16* Kp   = (_Float16*)(ws + (2u << 20));        // 2 MB
  _Float16* Vt2  = (_Float16*)(ws + (4u << 20));        // 2 MB
  _Float16* Of16 = (_Float16*)(ws + (6u << 20));        // 2 MB
  float*    lsum = (float*)(ws + (8u << 20));           // 128 KB

  const float scale_q = 0.17677669529663687f * LOG2E_FOLD;

  k1_proj_vt<<<dim3(1024), dim3(256), 0, stream>>>(query, key, value, Wq, Wk,
                                                   bq, bk, Qp, Kp, Vt2, scale_q);
  attn_o_kernel<<<dim3(512), dim3(512), 0, stream>>>(Qp, Kp, Vt2, Of16, lsum);
  k3_avg_outproj<<<dim3(640), dim3(512), 0, stream>>>(Qp, Kp, lsum, Of16, Wo, bo,
                                                      avg_out, out);
}